// Round 3
// baseline (1022.303 us; speedup 1.0000x reference)
//
#include <hip/hip_runtime.h>
#include <hip/hip_cooperative_groups.h>
#include <math.h>

#define BB 64
#define SS 2048
#define HH 1024
#define LL 15
#define NBLK 512
#define LSTR 68

namespace cg = cooperative_groups;

// ---------------- 64x64 GEMM tile, k-major LDS, register double-buffer ----------------
// C[0:64, j0:j0+64] += A[0:64, k0:kend] @ W[k0:kend, j0:j0+64]  (atomic accumulate)
// 256 threads as 16x16, each a 4x4 micro-tile. LDS stride 68 keeps float4 alignment
// (68*4=272 B, mult of 16) while breaking power-of-2 bank strides.
__device__ __forceinline__ void gemm_tile_body(
    const float* __restrict__ A, int lda,
    const float* __restrict__ W, int ldw,
    const float* __restrict__ bias,
    float* __restrict__ C, int ldc,
    int k0, int kend, int j0, bool addBias) {
  __shared__ float As[32 * LSTR];  // [kk][row]
  __shared__ float Ws[32 * LSTR];  // [kk][col]
  int tid = threadIdx.x;
  int tx = tid & 15, ty = tid >> 4;

  float4 aReg[2], wReg[2];
  int aRow[2], aKq[2], wRow[2], wCq[2];
#pragma unroll
  for (int i = 0; i < 2; ++i) {
    int idx = tid + i * 256;
    aRow[i] = idx & 63; aKq[i] = idx >> 6;
    wRow[i] = idx >> 4; wCq[i] = idx & 15;
  }

  auto loadRegs = [&](int kb) {
#pragma unroll
    for (int i = 0; i < 2; ++i) {
      aReg[i] = *(const float4*)&A[(size_t)aRow[i] * lda + kb + 4 * aKq[i]];
      wReg[i] = *(const float4*)&W[(size_t)(kb + wRow[i]) * ldw + j0 + 4 * wCq[i]];
    }
  };

  float acc[4][4] = {{0.f}};
  loadRegs(k0);
  for (int kb = k0; kb < kend; kb += 32) {
#pragma unroll
    for (int i = 0; i < 2; ++i) {
      float av[4] = {aReg[i].x, aReg[i].y, aReg[i].z, aReg[i].w};
#pragma unroll
      for (int j = 0; j < 4; ++j) As[(4 * aKq[i] + j) * LSTR + aRow[i]] = av[j];
      *(float4*)&Ws[wRow[i] * LSTR + 4 * wCq[i]] = wReg[i];
    }
    __syncthreads();
    if (kb + 32 < kend) loadRegs(kb + 32);  // prefetch next k-block while computing
#pragma unroll
    for (int kk = 0; kk < 32; ++kk) {
      float4 a4 = *(const float4*)&As[kk * LSTR + ty * 4];
      float4 w4 = *(const float4*)&Ws[kk * LSTR + tx * 4];
      float a[4] = {a4.x, a4.y, a4.z, a4.w};
      float w[4] = {w4.x, w4.y, w4.z, w4.w};
#pragma unroll
      for (int i = 0; i < 4; ++i)
#pragma unroll
        for (int j = 0; j < 4; ++j) acc[i][j] += a[i] * w[j];
    }
    __syncthreads();
  }
#pragma unroll
  for (int i = 0; i < 4; ++i) {
    int r = ty * 4 + i;
#pragma unroll
    for (int j = 0; j < 4; ++j) {
      int c = j0 + tx * 4 + j;
      float v = acc[i][j];
      if (addBias) v += bias[c];
      atomicAdd(&C[(size_t)r * ldc + c], v);
    }
  }
}

// ---------------- single cooperative kernel: all 5 stages, 4 grid syncs ----------------
// 512 blocks x 256 threads, 2 blocks/CU co-resident (LDS 17.4 KB/block).
__global__ void fused_kernel(const float* __restrict__ x,
                             const int* __restrict__ eidx,
                             const float* __restrict__ W_cls, const float* __restrict__ b_cls,
                             const float* __restrict__ W_e1,  const float* __restrict__ b_e1,
                             const float* __restrict__ W_e2,  const float* __restrict__ b_e2,
                             const float* __restrict__ W1,    const float* __restrict__ b1,
                             const float* __restrict__ W2,    const float* __restrict__ b2,
                             const float* __restrict__ Wout,  const float* __restrict__ bout,
                             float* __restrict__ out,
                             float* __restrict__ t_cat,
                             float* __restrict__ h_cat,   // h_cat, h1, h2 contiguous
                             float* __restrict__ h1,
                             float* __restrict__ h2) {
  cg::grid_group grid = cg::this_grid();
  int blk = blockIdx.x;
  int tid = threadIdx.x;

  // ---- Stage A: zero h_cat/h1/h2 (contiguous 327680 floats) + spans/tanh ----
  {
    const float4 zero4 = {0.f, 0.f, 0.f, 0.f};
    int zidx = blk * 256 + tid;  // one float4 per thread, 81920 needed of 131072
    if (zidx < (BB * 5 * HH) / 4) ((float4*)h_cat)[zidx] = zero4;

    if (blk < 2 * BB) {
      int b = blk & 63;
      int part = blk >> 6;
      int h4 = tid * 4;
      const float* xb = x + (size_t)b * SS * HH;
      float* tb = t_cat + (size_t)b * 3 * HH;
      if (part == 0) {
        int s1 = eidx[b * 4 + 0], e1 = eidx[b * 4 + 1];
        float c1 = (float)max(e1 - s1, 1);
        float4 v0 = *(const float4*)&xb[h4];
        float4 a = zero4;
        for (int s = s1; s < e1; ++s) {
          float4 v = *(const float4*)&xb[(size_t)s * HH + h4];
          a.x += v.x; a.y += v.y; a.z += v.z; a.w += v.w;
        }
        float4 o0 = {tanhf(v0.x), tanhf(v0.y), tanhf(v0.z), tanhf(v0.w)};
        *(float4*)&tb[h4] = o0;
        float4 o1 = {tanhf(a.x / c1), tanhf(a.y / c1), tanhf(a.z / c1), tanhf(a.w / c1)};
        *(float4*)&tb[HH + h4] = o1;
      } else {
        int s2 = eidx[b * 4 + 2], e2 = eidx[b * 4 + 3];
        float c2 = (float)max(e2 - s2, 1);
        float4 a = zero4;
        for (int s = s2; s < e2; ++s) {
          float4 v = *(const float4*)&xb[(size_t)s * HH + h4];
          a.x += v.x; a.y += v.y; a.z += v.z; a.w += v.w;
        }
        float4 o2 = {tanhf(a.x / c2), tanhf(a.y / c2), tanhf(a.z / c2), tanhf(a.w / c2)};
        *(float4*)&tb[2 * HH + h4] = o2;
      }
    }
  }
  grid.sync();

  // ---- Stage B: block-diag [64,3072]->[64,3072]; 16j x 3z x KS=8 (Kchunk 128) = 384 jobs
  if (blk < 384) {
    int jcol = blk & 15;
    int rest = blk >> 4;       // 0..23
    int ks = rest & 7;         // 0..7
    int z = rest >> 3;         // 0..2
    const float* W = (z == 0) ? W_cls : ((z == 1) ? W_e1 : W_e2);
    const float* bias = (z == 0) ? b_cls : ((z == 1) ? b_e1 : b_e2);
    gemm_tile_body(t_cat + z * HH, 3 * HH, W, HH, bias, h_cat + z * HH, 3 * HH,
                   ks * 128, ks * 128 + 128, jcol * 64, ks == 0);
  }
  grid.sync();

  // ---- Stage C: [64,3072]@[3072,1024]; 16j x KS=32 (Kchunk 96) = 512 jobs
  {
    int jcol = blk & 15;
    int ks = blk >> 4;  // 0..31
    gemm_tile_body(h_cat, 3 * HH, W1, HH, b1, h1, HH,
                   ks * 96, ks * 96 + 96, jcol * 64, ks == 0);
  }
  grid.sync();

  // ---- Stage D: [64,1024]@[1024,1024]; 16j x KS=32 (Kchunk 32) = 512 jobs
  {
    int jcol = blk & 15;
    int ks = blk >> 4;  // 0..31
    gemm_tile_body(h1, HH, W2, HH, b2, h2, HH,
                   ks * 32, ks * 32 + 32, jcol * 64, ks == 0);
  }
  grid.sync();

  // ---- Stage E: [64,1024]@[1024,15]; one wave per output, 960 of 2048 waves
  {
    int lane = tid & 63;
    int idx = blk * 4 + (tid >> 6);
    if (idx < BB * LL) {
      int b = idx / LL, l = idx % LL;
      const float* h = h2 + (size_t)b * HH;
      float acc = 0.f;
#pragma unroll
      for (int w = 0; w < 4; ++w) {
        int k0 = (w * 64 + lane) * 4;
        float4 hv = *(const float4*)&h[k0];
        acc += hv.x * Wout[(size_t)(k0 + 0) * LL + l];
        acc += hv.y * Wout[(size_t)(k0 + 1) * LL + l];
        acc += hv.z * Wout[(size_t)(k0 + 2) * LL + l];
        acc += hv.w * Wout[(size_t)(k0 + 3) * LL + l];
      }
#pragma unroll
      for (int off = 32; off > 0; off >>= 1) acc += __shfl_down(acc, off, 64);
      if (lane == 0) out[idx] = acc + bout[l];
    }
  }
}

extern "C" void kernel_launch(void* const* d_in, const int* in_sizes, int n_in,
                              void* d_out, int out_size, void* d_ws, size_t ws_size,
                              hipStream_t stream) {
  const float* x     = (const float*)d_in[0];
  const int*   eidx  = (const int*)d_in[1];
  const float* W_cls = (const float*)d_in[2];
  const float* b_cls = (const float*)d_in[3];
  const float* W_e1  = (const float*)d_in[4];
  const float* b_e1  = (const float*)d_in[5];
  const float* W_e2  = (const float*)d_in[6];
  const float* b_e2  = (const float*)d_in[7];
  const float* W1    = (const float*)d_in[8];
  const float* b1    = (const float*)d_in[9];
  const float* W2    = (const float*)d_in[10];
  const float* b2    = (const float*)d_in[11];
  const float* Wout  = (const float*)d_in[12];
  const float* bout  = (const float*)d_in[13];
  float* out = (float*)d_out;

  float* ws    = (float*)d_ws;
  float* t_cat = ws;                          // 64*3072
  float* h_cat = t_cat + BB * 3 * HH;         // 64*3072 (atomic-accumulated)
  float* h1    = h_cat + BB * 3 * HH;         // 64*1024 (atomic-accumulated)
  float* h2    = h1 + BB * HH;                // 64*1024 (atomic-accumulated)

  void* args[] = {
      (void*)&x, (void*)&eidx,
      (void*)&W_cls, (void*)&b_cls, (void*)&W_e1, (void*)&b_e1,
      (void*)&W_e2, (void*)&b_e2, (void*)&W1, (void*)&b1,
      (void*)&W2, (void*)&b2, (void*)&Wout, (void*)&bout,
      (void*)&out, (void*)&t_cat, (void*)&h_cat, (void*)&h1, (void*)&h2};
  hipLaunchCooperativeKernel((void*)fused_kernel, dim3(NBLK), dim3(256),
                             args, 0, stream);
}